// Round 9
// baseline (240.589 us; speedup 1.0000x reference)
//
#include <hip/hip_runtime.h>
#include <math.h>

#define BB 4096
#define DD 128
#define KLO 0x3E7FFFFFu     /* fkey(-16.0f) */
#define KHI 0xC1800000u     /* fkey(+16.0f) */
#define SH0 20              /* first-level bin shift: 2096 bins over [KLO,KHI] */
#define CHUNK 9             /* bins per thread in scan */
#define NBALLOC 2304        /* 9*256, zero-padded hist allocation */

typedef __attribute__((ext_vector_type(8))) short bf16x8;
typedef __attribute__((ext_vector_type(4))) float f32x4;

__device__ __forceinline__ unsigned fkey(float x){
    int b = __float_as_int(x);
    return (unsigned)(b ^ ((b >> 31) | 0x80000000));
}
__device__ __forceinline__ float funkey(unsigned u){
    unsigned b = (u & 0x80000000u) ? (u & 0x7fffffffu) : ~u;
    return __uint_as_float(b);
}

__device__ __forceinline__ float blkSumF(float v, volatile float* sh){
    #pragma unroll
    for (int o = 32; o > 0; o >>= 1) v += __shfl_down(v, o);
    int t = threadIdx.x;
    __syncthreads();
    if ((t & 63) == 0) sh[t >> 6] = v;
    __syncthreads();
    return (sh[0] + sh[1]) + (sh[2] + sh[3]);
}
__device__ __forceinline__ int blkSumI(int v, volatile int* sh){
    #pragma unroll
    for (int o = 32; o > 0; o >>= 1) v += __shfl_down(v, o);
    int t = threadIdx.x;
    __syncthreads();
    if ((t & 63) == 0) sh[t >> 6] = v;
    __syncthreads();
    return (sh[0] + sh[1]) + (sh[2] + sh[3]);
}

// ---------- normalize -> bf16, stored with XOR-swizzled column ----------
__global__ void krn_normalize(const float* __restrict__ drug, const float* __restrict__ se,
                              ushort* __restrict__ Z){
    int row = blockIdx.x, br = blockIdx.y, t = threadIdx.x;  // blockDim = 128
    float dv = drug[row * DD + t];
    float sv = se[row * DD + t];
    float v = (br == 0) ? dv : ((br == 1) ? sv : dv * sv);
    float sq = v * v;
    #pragma unroll
    for (int o = 32; o > 0; o >>= 1) sq += __shfl_down(sq, o);
    __shared__ float sh[2];
    if ((t & 63) == 0) sh[t >> 6] = sq;
    __syncthreads();
    float nrm = sqrtf(sh[0] + sh[1]);
    float outv = v / fmaxf(nrm, 1e-12f);
    unsigned u = __float_as_uint(outv);
    unsigned r = (u + 0x7FFFu + ((u >> 16) & 1u)) >> 16;   // RNE bf16
    int col = t ^ ((row & 7) << 3);
    Z[((size_t)br * BB + row) * DD + col] = (ushort)r;
}

// ---------- per-row label stats: NC[i], PWS[i] (self excluded), total negs ----------
__global__ __launch_bounds__(256) void krn_labelstats(const float* __restrict__ labels,
                                                      int* __restrict__ NC,
                                                      float* __restrict__ PWS,
                                                      int* __restrict__ ntot){
    __shared__ float lab[BB];
    __shared__ int shi[4];
    __shared__ float shf[4];
    int t = threadIdx.x;
    #pragma unroll
    for (int e = 0; e < 4; ++e)
        ((float4*)lab)[t + e * 256] = ((const float4*)labels)[t + e * 256];
    __syncthreads();
    int i0 = blockIdx.x * 16;
    int ctot = 0;
    for (int ii = 0; ii < 16; ++ii){
        float li = lab[i0 + ii];
        int c = 0;
        float pws = 0.f;
        #pragma unroll
        for (int e = 0; e < 16; ++e){
            float d = fabsf(li - lab[t + e * 256]);
            c += (d > 1.0f) ? 1 : 0;
            pws += __expf(d * (-1.0f / 0.15f));
        }
        int C = blkSumI(c, shi);
        float P = blkSumF(pws, shf);
        if (t == 0){
            NC[i0 + ii] = C;
            PWS[i0 + ii] = P - 1.0f;   // exclude self (expf(-0)=1 exactly)
            ctot += C;
        }
    }
    if (t == 0) atomicAdd(ntot, ctot);
}

__global__ void krn_calck(const int* __restrict__ ntot, int* __restrict__ kflags){
    int N = *ntot;
    int k = N >> 13;            // trunc((N/4096)*0.5), exact
    if (k < 1) k = 1;
    if (k > BB - 1) k = BB - 1;
    kflags[0] = k;
    kflags[1] = (N > 0) ? 1 : 0;
}

// ---------- bf16 MFMA GEMM: sim[z][slab x BB] = (Z_z Z_z^T)/T ----------
__device__ __forceinline__ bf16x8 frag_ld(const ushort* base, int row, int e0){
    int e = e0 ^ ((row & 7) << 3);
    return *(const bf16x8*)(base + row * DD + e);
}

__global__ __launch_bounds__(256) void krn_gemm(const ushort* __restrict__ Z,
                                                float* __restrict__ sim, size_t simStride,
                                                int r0){
    __shared__ ushort As[128 * DD];
    __shared__ ushort Bs[128 * DD];
    const ushort* Zb = Z + (size_t)blockIdx.z * (BB * DD);
    float* simz = sim + (size_t)blockIdx.z * simStride;
    int t = threadIdx.x;
    int rowbase = r0 + blockIdx.y * 128;
    int colbase = blockIdx.x * 128;

    {
        const float4* gA = (const float4*)(Zb + (size_t)rowbase * DD);
        const float4* gB = (const float4*)(Zb + (size_t)colbase * DD);
        float4* lA = (float4*)As;
        float4* lB = (float4*)Bs;
        #pragma unroll
        for (int it = 0; it < 8; ++it){
            lA[it * 256 + t] = gA[it * 256 + t];
            lB[it * 256 + t] = gB[it * 256 + t];
        }
    }
    __syncthreads();

    int wid = t >> 6, lane = t & 63;
    int wr = (wid >> 1) * 64, wc = (wid & 1) * 64;
    int fr = lane & 15, fq = lane >> 4;

    f32x4 acc[4][4];
    #pragma unroll
    for (int m = 0; m < 4; ++m)
        #pragma unroll
        for (int n = 0; n < 4; ++n)
            acc[m][n] = (f32x4){0.f, 0.f, 0.f, 0.f};

    #pragma unroll
    for (int ks = 0; ks < 4; ++ks){
        int e0 = ks * 32 + fq * 8;
        bf16x8 a0 = frag_ld(As, wr + 0 * 16 + fr, e0);
        bf16x8 a1 = frag_ld(As, wr + 1 * 16 + fr, e0);
        bf16x8 a2 = frag_ld(As, wr + 2 * 16 + fr, e0);
        bf16x8 a3 = frag_ld(As, wr + 3 * 16 + fr, e0);
        bf16x8 b0 = frag_ld(Bs, wc + 0 * 16 + fr, e0);
        bf16x8 b1 = frag_ld(Bs, wc + 1 * 16 + fr, e0);
        bf16x8 b2 = frag_ld(Bs, wc + 2 * 16 + fr, e0);
        bf16x8 b3 = frag_ld(Bs, wc + 3 * 16 + fr, e0);
        acc[0][0] = __builtin_amdgcn_mfma_f32_16x16x32_bf16(a0, b0, acc[0][0], 0, 0, 0);
        acc[0][1] = __builtin_amdgcn_mfma_f32_16x16x32_bf16(a0, b1, acc[0][1], 0, 0, 0);
        acc[0][2] = __builtin_amdgcn_mfma_f32_16x16x32_bf16(a0, b2, acc[0][2], 0, 0, 0);
        acc[0][3] = __builtin_amdgcn_mfma_f32_16x16x32_bf16(a0, b3, acc[0][3], 0, 0, 0);
        acc[1][0] = __builtin_amdgcn_mfma_f32_16x16x32_bf16(a1, b0, acc[1][0], 0, 0, 0);
        acc[1][1] = __builtin_amdgcn_mfma_f32_16x16x32_bf16(a1, b1, acc[1][1], 0, 0, 0);
        acc[1][2] = __builtin_amdgcn_mfma_f32_16x16x32_bf16(a1, b2, acc[1][2], 0, 0, 0);
        acc[1][3] = __builtin_amdgcn_mfma_f32_16x16x32_bf16(a1, b3, acc[1][3], 0, 0, 0);
        acc[2][0] = __builtin_amdgcn_mfma_f32_16x16x32_bf16(a2, b0, acc[2][0], 0, 0, 0);
        acc[2][1] = __builtin_amdgcn_mfma_f32_16x16x32_bf16(a2, b1, acc[2][1], 0, 0, 0);
        acc[2][2] = __builtin_amdgcn_mfma_f32_16x16x32_bf16(a2, b2, acc[2][2], 0, 0, 0);
        acc[2][3] = __builtin_amdgcn_mfma_f32_16x16x32_bf16(a2, b3, acc[2][3], 0, 0, 0);
        acc[3][0] = __builtin_amdgcn_mfma_f32_16x16x32_bf16(a3, b0, acc[3][0], 0, 0, 0);
        acc[3][1] = __builtin_amdgcn_mfma_f32_16x16x32_bf16(a3, b1, acc[3][1], 0, 0, 0);
        acc[3][2] = __builtin_amdgcn_mfma_f32_16x16x32_bf16(a3, b2, acc[3][2], 0, 0, 0);
        acc[3][3] = __builtin_amdgcn_mfma_f32_16x16x32_bf16(a3, b3, acc[3][3], 0, 0, 0);
    }

    const float invT = 1.0f / 0.07f;
    int srow0 = blockIdx.y * 128 + wr + fq * 4;
    int scol0 = colbase + wc + fr;
    #pragma unroll
    for (int m = 0; m < 4; ++m){
        #pragma unroll
        for (int n = 0; n < 4; ++n){
            f32x4 c = acc[m][n];
            #pragma unroll
            for (int j = 0; j < 4; ++j)
                simz[(size_t)(srow0 + m * 16 + j) * BB + scol0 + n * 16] = c[j] * invT;
        }
    }
}

// ---------- per-(branch,row) stats: fused hist + psim/max + exact select + LSE ----------
__global__ __launch_bounds__(256) void krn_stats(const float* __restrict__ sim, size_t simStride,
                                                 const float* __restrict__ labels,
                                                 const int* __restrict__ NCg,
                                                 const float* __restrict__ PWSg,
                                                 const int* __restrict__ kflags,
                                                 float* __restrict__ rowloss, int r0){
    __shared__ int hist[NBALLOC];
    __shared__ int wsum[4];
    __shared__ float redm[4], redb[4];
    __shared__ float redf[4];
    __shared__ unsigned selb[3];
    __shared__ unsigned sel2[2];
    __shared__ int cnt;
    __shared__ unsigned list[96];

    int t = threadIdx.x;
    int bi = blockIdx.y;
    int row = blockIdx.x;
    int i = r0 + row;
    float li = labels[i];

    #pragma unroll
    for (int e = 0; e < CHUNK; ++e) hist[t + e * 256] = 0;
    __syncthreads();

    const float* srow = sim + (size_t)bi * simStride + (size_t)row * BB;
    const float4* sp = (const float4*)srow;
    const float4* lp = (const float4*)labels;

    float s[16];
    unsigned negbits = 0, posbits = 0;
    float m = -INFINITY, psim = 0.f;

    // pass A: loads + label work + psim + fixed-range neg histogram
    // (self included in pos/psim with pw=expf(-0)=1; corrected at end)
    #pragma unroll
    for (int e = 0; e < 4; ++e){
        float4 sv = sp[t + e * 256];
        float4 lv = lp[t + e * 256];
        float sc[4] = {sv.x, sv.y, sv.z, sv.w};
        float lc[4] = {lv.x, lv.y, lv.z, lv.w};
        #pragma unroll
        for (int c = 0; c < 4; ++c){
            int idx = e * 4 + c;
            float v = sc[c];
            s[idx] = v;
            m = fmaxf(m, v);
            float d = fabsf(li - lc[c]);
            float pw = __expf(d * (-1.0f / 0.15f));
            psim = fmaf(pw, v, psim);
            if (d > 1.0f){
                negbits |= 1u << idx;
                atomicAdd(&hist[(fkey(v) - KLO) >> SH0], 1);
            } else if (d < 0.34538776f){
                posbits |= 1u << idx;     // pw > 0.1 (self flagged; corrected at end)
            }
        }
    }

    // fused 2-quantity block reduction (barriers also order hist atomics)
    #pragma unroll
    for (int o = 32; o > 0; o >>= 1){
        m = fmaxf(m, __shfl_down(m, o));
        psim += __shfl_down(psim, o);
    }
    __syncthreads();
    if ((t & 63) == 0){
        int w = t >> 6;
        redm[w] = m; redb[w] = psim;
    }
    __syncthreads();
    float M    = fmaxf(fmaxf(redm[0], redm[1]), fmaxf(redm[2], redm[3]));
    float PSIM = (redb[0] + redb[1]) + (redb[2] + redb[3]);

    int kk = kflags[0], anyneg = kflags[1];
    int NCv = NCg[i];
    int mode = anyneg ? ((NCv <= kk) ? 1 : 0) : 2;   // 0: top-k, 1: all negs, 2: self_mask

    unsigned ukth = 0;
    int rfin = 0;
    if (mode == 0){
        unsigned klo = KLO, khi = KHI;
        int sh = SH0;
        int rp = kk;
        bool ready = true;   // first-level hist pre-filled in pass A
        while (true){
            if (klo == khi){ ukth = klo; rfin = rp; break; }
            if (!ready){
                #pragma unroll
                for (int e = 0; e < CHUNK; ++e) hist[t + e * 256] = 0;
                __syncthreads();
                #pragma unroll
                for (int idx = 0; idx < 16; ++idx){
                    if (negbits & (1u << idx)){
                        unsigned u = fkey(s[idx]);
                        if (u >= klo && u <= khi)
                            atomicAdd(&hist[(u - klo) >> sh], 1);
                    }
                }
                __syncthreads();
            }
            ready = false;
            // chunked suffix scan: thread t owns chunk g=255-t, bins [g*CHUNK, g*CHUNK+CHUNK)
            int g = 255 - t;
            int base = g * CHUNK;
            int ls = 0;
            #pragma unroll
            for (int e = 0; e < CHUNK; ++e) ls += hist[base + e];
            int v = ls;
            #pragma unroll
            for (int o = 1; o < 64; o <<= 1){
                int u2 = __shfl_up(v, o);
                if ((t & 63) >= o) v += u2;
            }
            if ((t & 63) == 63) wsum[t >> 6] = v;
            __syncthreads();
            int w = t >> 6;
            int pre = (w > 0 ? wsum[0] : 0) + (w > 1 ? wsum[1] : 0) + (w > 2 ? wsum[2] : 0);
            v += pre;                 // inclusive count over chunks >= g
            int aec = v - ls;         // strictly-above-chunk count
            if (aec < rp && rp <= v){
                int cum = aec;        // walk bins high -> low inside this chunk
                #pragma unroll
                for (int e = CHUNK - 1; e >= 0; --e){
                    int c = hist[base + e];
                    if (cum < rp && rp <= cum + c){
                        selb[0] = (unsigned)(base + e);
                        selb[1] = (unsigned)cum;
                        selb[2] = (unsigned)c;
                        break;
                    }
                    cum += c;
                }
            }
            __syncthreads();
            unsigned B = selb[0];
            int ae = (int)selb[1];
            int c  = (int)selb[2];
            rp -= ae;
            klo += B << sh;
            unsigned nhi = klo + ((1u << sh) - 1u);
            if (nhi < khi) khi = nhi;
            if (c <= 96){
                if (t == 0) cnt = 0;
                __syncthreads();
                #pragma unroll
                for (int idx = 0; idx < 16; ++idx){
                    if (negbits & (1u << idx)){
                        unsigned u = fkey(s[idx]);
                        if (u >= klo && u <= khi){
                            int p = atomicAdd(&cnt, 1);
                            list[p] = u;
                        }
                    }
                }
                __syncthreads();
                int cc = cnt;
                if (t < cc){
                    unsigned kj = list[t];
                    int g2 = 0, e2 = 0;
                    for (int mm = 0; mm < cc; ++mm){
                        unsigned km = list[mm];
                        g2 += (km > kj) ? 1 : 0;
                        e2 += (km == kj) ? 1 : 0;
                    }
                    if (g2 < rp && rp <= g2 + e2){ sel2[0] = kj; sel2[1] = (unsigned)g2; }
                }
                __syncthreads();
                ukth = sel2[0];
                rfin = rp - (int)sel2[1];
                break;
            }
            {   // refine: pick new shift so bins <= 2048
                unsigned range = khi - klo;
                int bits = 32 - __clz(range);
                sh = (bits > 11) ? (bits - 11) : 0;
            }
            __syncthreads();
        }
    }

    // denominator: sum exp(s - M) over denom mask (self corrected at end)
    float skth = (mode == 0) ? funkey(ukth) : INFINITY;
    unsigned em = (mode == 2) ? 0xFFFFu : ((mode == 1) ? (negbits | posbits) : posbits);
    float El = 0.f;
    #pragma unroll
    for (int idx = 0; idx < 16; ++idx){
        unsigned bit = 1u << idx;
        bool dm = (em & bit) != 0u;
        if (negbits & bit) dm = dm || (s[idx] > skth);
        if (dm) El += __expf(s[idx] - M);
    }
    float Etot = blkSumF(El, redf);

    if (t == 0){
        if (mode == 0) Etot += (float)rfin * __expf(skth - M);
        float s_self = srow[i];
        Etot -= __expf(s_self - M);          // self was in pos/full sets
        float PWSc  = PWSg[i];               // already self-excluded
        float PSIMc = PSIM - s_self;         // pw(i,i) = expf(-0) = 1 exactly
        float logE = __logf(Etot + 1e-8f);
        float wl = (PSIMc - M * PWSc) - PWSc * logE;
        rowloss[bi * BB + i] = wl / fmaxf(PWSc, 1e-8f);
    }
}

// ---------- final deterministic reduction ----------
__global__ void krn_final(const float* __restrict__ rowloss, float* __restrict__ out){
    __shared__ float redf[4];
    int t = threadIdx.x;  // 256
    float total = 0.f;
    for (int b = 0; b < 3; ++b){
        float ssum = 0.f;
        for (int e = 0; e < 16; ++e) ssum += rowloss[b * BB + t + e * 256];
        float S = blkSumF(ssum, redf);
        total += S * (1.0f / BB);
    }
    if (t == 0) out[0] = -total / 3.0f;
}

extern "C" void kernel_launch(void* const* d_in, const int* in_sizes, int n_in,
                              void* d_out, int out_size, void* d_ws, size_t ws_size,
                              hipStream_t stream){
    const float* drug   = (const float*)d_in[0];
    const float* se     = (const float*)d_in[1];
    const float* labels = (const float*)d_in[2];
    float* out = (float*)d_out;
    char* ws = (char*)d_ws;

    const size_t zbytes = (size_t)3 * BB * DD * sizeof(ushort);    // 3 MB bf16
    const size_t tail   = (size_t)(3 + 1 + 1) * BB * sizeof(float) + 256;

    // slab=1024: 3-branch sim working set = 50 MB -> Infinity-Cache resident
    int slab = 1024;
    while (slab > 128 && zbytes + tail + (size_t)3 * slab * BB * sizeof(float) > ws_size)
        slab >>= 1;
    size_t simStride = (size_t)slab * BB;

    ushort* Z      = (ushort*)ws;
    float* simbuf  = (float*)(ws + zbytes);
    size_t off     = zbytes + (size_t)3 * simStride * sizeof(float);
    float* rowloss = (float*)(ws + off);  off += (size_t)3 * BB * sizeof(float);
    float* PWSb    = (float*)(ws + off);  off += (size_t)BB * sizeof(float);
    int*   NCb     = (int*)(ws + off);    off += (size_t)BB * sizeof(int);
    int*   ntot    = (int*)(ws + off);
    int*   kflags  = ntot + 2;

    hipMemsetAsync(ntot, 0, 2 * sizeof(int), stream);
    krn_normalize<<<dim3(BB, 3), 128, 0, stream>>>(drug, se, Z);
    krn_labelstats<<<256, 256, 0, stream>>>(labels, NCb, PWSb, ntot);
    krn_calck<<<1, 1, 0, stream>>>(ntot, kflags);

    int nslab = BB / slab;
    for (int s2 = 0; s2 < nslab; ++s2){
        krn_gemm<<<dim3(BB / 128, slab / 128, 3), 256, 0, stream>>>(Z, simbuf, simStride, s2 * slab);
        krn_stats<<<dim3(slab, 3), 256, 0, stream>>>(simbuf, simStride, labels,
                                                     NCb, PWSb, kflags, rowloss, s2 * slab);
    }
    krn_final<<<1, 256, 0, stream>>>(rowloss, out);
}

// Round 10
// 189.356 us; speedup vs baseline: 1.2706x; 1.2706x over previous
//
#include <hip/hip_runtime.h>
#include <math.h>

#define BB 4096
#define DD 128
#define KLO 0x3E7FFFFFu     /* fkey(-16.0f) */
#define KHI 0xC1800000u     /* fkey(+16.0f) */
#define SH0 19              /* first-level bin shift: 4193 bins over [KLO,KHI] */
#define CHUNK 17
#define NBALLOC 4352        /* 17*256 zero-padded hist allocation */

typedef __attribute__((ext_vector_type(8))) short bf16x8;
typedef __attribute__((ext_vector_type(4))) float f32x4;

__device__ __forceinline__ unsigned fkey(float x){
    int b = __float_as_int(x);
    return (unsigned)(b ^ ((b >> 31) | 0x80000000));
}
__device__ __forceinline__ float funkey(unsigned u){
    unsigned b = (u & 0x80000000u) ? (u & 0x7fffffffu) : ~u;
    return __uint_as_float(b);
}
__device__ __forceinline__ float bf16f(ushort u){
    return __uint_as_float(((unsigned)u) << 16);
}

__device__ __forceinline__ float blkSumF(float v, volatile float* sh){
    #pragma unroll
    for (int o = 32; o > 0; o >>= 1) v += __shfl_down(v, o);
    int t = threadIdx.x;
    __syncthreads();
    if ((t & 63) == 0) sh[t >> 6] = v;
    __syncthreads();
    return (sh[0] + sh[1]) + (sh[2] + sh[3]);
}

// ---------- normalize -> bf16 (XOR-swizzled col) + wp/wm tables ----------
__global__ void krn_normalize(const float* __restrict__ drug, const float* __restrict__ se,
                              const float* __restrict__ labels,
                              ushort* __restrict__ Z,
                              float* __restrict__ wp, float* __restrict__ wm){
    int row = blockIdx.x, br = blockIdx.y, t = threadIdx.x;  // blockDim = 128
    float dv = drug[row * DD + t];
    float sv = se[row * DD + t];
    float v = (br == 0) ? dv : ((br == 1) ? sv : dv * sv);
    float sq = v * v;
    #pragma unroll
    for (int o = 32; o > 0; o >>= 1) sq += __shfl_down(sq, o);
    __shared__ float sh[2];
    if ((t & 63) == 0) sh[t >> 6] = sq;
    __syncthreads();
    float nrm = sqrtf(sh[0] + sh[1]);
    float outv = v / fmaxf(nrm, 1e-12f);
    unsigned u = __float_as_uint(outv);
    unsigned r = (u + 0x7FFFu + ((u >> 16) & 1u)) >> 16;   // RNE bf16
    int col = t ^ ((row & 7) << 3);
    Z[((size_t)br * BB + row) * DD + col] = (ushort)r;
    if (br == 0 && t == 0){
        float l = labels[row];
        wp[row] = __expf(l * (1.0f / 0.15f));
        wm[row] = __expf(l * (-1.0f / 0.15f));
    }
}

// ---------- label stats: NC[i], PWS[i] (self-excl), ntot, label-sort perm ----------
__global__ __launch_bounds__(256) void krn_labelstats(const float* __restrict__ labels,
                                                      int* __restrict__ NC,
                                                      float* __restrict__ PWS,
                                                      int* __restrict__ perm,
                                                      int* __restrict__ ntot){
    __shared__ float lab[BB];
    __shared__ int shi[4], shr[4];
    __shared__ float shf[4];
    int t = threadIdx.x;
    #pragma unroll
    for (int e = 0; e < 4; ++e)
        ((float4*)lab)[t + e * 256] = ((const float4*)labels)[t + e * 256];
    __syncthreads();
    int i0 = blockIdx.x * 16;
    int ctot = 0;
    for (int ii = 0; ii < 16; ++ii){
        int i = i0 + ii;
        float li = lab[i];
        int c = 0, rk = 0;
        float pws = 0.f;
        #pragma unroll
        for (int e = 0; e < 16; ++e){
            int j = t + e * 256;
            float lj = lab[j];
            float d = fabsf(li - lj);
            c += (d > 1.0f) ? 1 : 0;
            pws += __expf(d * (-1.0f / 0.15f));
            rk += (lj < li || (lj == li && j < i)) ? 1 : 0;
        }
        #pragma unroll
        for (int o = 32; o > 0; o >>= 1){
            c += __shfl_down(c, o);
            rk += __shfl_down(rk, o);
            pws += __shfl_down(pws, o);
        }
        __syncthreads();
        if ((t & 63) == 0){ int w = t >> 6; shi[w] = c; shr[w] = rk; shf[w] = pws; }
        __syncthreads();
        if (t == 0){
            int C = (shi[0] + shi[1]) + (shi[2] + shi[3]);
            int R = (shr[0] + shr[1]) + (shr[2] + shr[3]);
            float P = (shf[0] + shf[1]) + (shf[2] + shf[3]);
            NC[i] = C;
            PWS[i] = P - 1.0f;   // exclude self (expf(-0)=1 exactly)
            perm[R] = i;
            ctot += C;
        }
    }
    if (t == 0) atomicAdd(ntot, ctot);
}

// ---------- bitmask tables (R8-proven): bit e*4+c covers j = 4t + 1024e + c ----------
__global__ __launch_bounds__(256) void krn_masks(const float* __restrict__ labels,
                                                 ushort* __restrict__ negmask,
                                                 ushort* __restrict__ posmask){
    __shared__ float lab[BB];
    int t = threadIdx.x;
    #pragma unroll
    for (int e = 0; e < 4; ++e)
        ((float4*)lab)[t + e * 256] = ((const float4*)labels)[t + e * 256];
    __syncthreads();
    float lj[16];
    #pragma unroll
    for (int e = 0; e < 4; ++e)
        #pragma unroll
        for (int c = 0; c < 4; ++c)
            lj[e * 4 + c] = lab[4 * t + 1024 * e + c];
    int i0 = blockIdx.x * 16;
    for (int ii = 0; ii < 16; ++ii){
        int i = i0 + ii;
        float li = lab[i];
        unsigned nb = 0, pb = 0;
        #pragma unroll
        for (int e = 0; e < 4; ++e){
            #pragma unroll
            for (int c = 0; c < 4; ++c){
                int idx = e * 4 + c;
                int j = 4 * t + 1024 * e + c;
                float d = fabsf(li - lj[idx]);
                if (d > 1.0f) nb |= 1u << idx;
                else if (d < 0.34538776f && j != i) pb |= 1u << idx;   // pw > 0.1
            }
        }
        negmask[i * 256 + t] = (ushort)nb;
        posmask[i * 256 + t] = (ushort)pb;
    }
}

__global__ void krn_calck(const int* __restrict__ ntot, int* __restrict__ kflags){
    int N = *ntot;
    int k = N >> 13;            // trunc((N/4096)*0.5), exact
    if (k < 1) k = 1;
    if (k > BB - 1) k = BB - 1;
    kflags[0] = k;
    kflags[1] = (N > 0) ? 1 : 0;
}

// ---------- sorted prefix/suffix scans: Yt[b][d][r] = wm_j*P<=r + wp_j*S>r ----------
__global__ __launch_bounds__(256) void krn_prefix(const ushort* __restrict__ Z,
                                                  const int* __restrict__ perm,
                                                  const float* __restrict__ wp,
                                                  const float* __restrict__ wm,
                                                  float* __restrict__ Yt){
    int d = blockIdx.x, b = blockIdx.y, t = threadIdx.x;
    const ushort* Zb = Z + (size_t)b * BB * DD;
    float uu[16], vv[16], wpj[16], wmj[16];
    float tu = 0.f, tv = 0.f;
    #pragma unroll
    for (int q = 0; q < 16; ++q){
        int r = t * 16 + q;
        int j = perm[r];
        int col = d ^ ((j & 7) << 3);
        float zv = bf16f(Zb[j * DD + col]);
        float a = wp[j], m2 = wm[j];
        wpj[q] = a; wmj[q] = m2;
        uu[q] = a * zv;  vv[q] = m2 * zv;
        tu += uu[q];     tv += vv[q];
    }
    int lane = t & 63, w = t >> 6;
    // ascending inclusive scan of tu, descending inclusive scan of tv (within wave)
    float xu = tu, xv = tv;
    #pragma unroll
    for (int o = 1; o < 64; o <<= 1){
        float y1 = __shfl_up(xu, o);   if (lane >= o)      xu += y1;
        float y2 = __shfl_down(xv, o); if (lane < 64 - o)  xv += y2;
    }
    __shared__ float wU[4], wV[4];
    if (lane == 63) wU[w] = xu;   // wave totals
    if (lane == 0)  wV[w] = xv;
    __syncthreads();
    float preU = 0.f, sufV = 0.f;
    #pragma unroll
    for (int ww = 0; ww < 4; ++ww){
        if (ww < w) preU += wU[ww];
        if (ww > w) sufV += wV[ww];
    }
    float offU   = preU + (xu - tu);   // exclusive prefix across threads
    float exSufV = sufV + (xv - tv);   // exclusive suffix across threads
    // element-level: suffix first (descending), overwrite vv with S
    float acc = 0.f;
    #pragma unroll
    for (int q = 15; q >= 0; --q){
        float S = exSufV + acc;
        acc += vv[q];
        vv[q] = S;
    }
    float* ytp = Yt + ((size_t)b * DD + d) * BB + t * 16;
    acc = 0.f;
    #pragma unroll
    for (int q = 0; q < 16; ++q){
        acc += uu[q];
        float P = offU + acc;                     // inclusive prefix (contains self)
        ytp[q] = wmj[q] * P + wpj[q] * vv[q];
    }
}

// ---------- PSIMc[b][j] = (z_j . y_j - wp_j*wm_j * z_j.z_j) / T ----------
__global__ __launch_bounds__(256) void krn_psim(const ushort* __restrict__ Z,
                                                const int* __restrict__ perm,
                                                const float* __restrict__ wp,
                                                const float* __restrict__ wm,
                                                const float* __restrict__ Yt,
                                                float* __restrict__ PSIMc){
    int b = blockIdx.y, r0 = blockIdx.x * 32, t = threadIdx.x;
    __shared__ float wt[32][129];
    #pragma unroll
    for (int q = 0; q < 16; ++q){
        int idx = t * 16 + q;
        int d = idx >> 5, r = idx & 31;
        wt[r][d] = Yt[((size_t)b * DD + d) * BB + r0 + r];
    }
    __syncthreads();
    int row = t >> 3, l8 = t & 7;
    int j = perm[r0 + row];
    const ushort* zr = Z + ((size_t)b * BB + j) * DD;
    int swz = (j & 7) << 3;
    float zy = 0.f, zz = 0.f;
    #pragma unroll
    for (int q = 0; q < 16; ++q){
        int d = l8 * 16 + q;
        float zv = bf16f(zr[d ^ swz]);
        float wv = wt[row][d];
        zy = fmaf(zv, wv, zy);
        zz = fmaf(zv, zv, zz);
    }
    #pragma unroll
    for (int o = 1; o < 8; o <<= 1){
        zy += __shfl_xor(zy, o);
        zz += __shfl_xor(zz, o);
    }
    if (l8 == 0)
        PSIMc[(size_t)b * BB + j] = (zy - wp[j] * wm[j] * zz) * (1.0f / 0.07f);
}

// ---------- bf16 MFMA GEMM (R4-proven, clean): sim[z] = (Z_z Z_z^T)/T ----------
__device__ __forceinline__ bf16x8 frag_ld(const ushort* base, int row, int e0){
    int e = e0 ^ ((row & 7) << 3);
    return *(const bf16x8*)(base + row * DD + e);
}

__global__ __launch_bounds__(256) void krn_gemm(const ushort* __restrict__ Z,
                                                float* __restrict__ sim, size_t simStride,
                                                int r0){
    __shared__ ushort As[128 * DD];
    __shared__ ushort Bs[128 * DD];
    const ushort* Zb = Z + (size_t)blockIdx.z * (BB * DD);
    float* simz = sim + (size_t)blockIdx.z * simStride;
    int t = threadIdx.x;
    int rowbase = r0 + blockIdx.y * 128;
    int colbase = blockIdx.x * 128;

    {
        const float4* gA = (const float4*)(Zb + (size_t)rowbase * DD);
        const float4* gB = (const float4*)(Zb + (size_t)colbase * DD);
        float4* lA = (float4*)As;
        float4* lB = (float4*)Bs;
        #pragma unroll
        for (int it = 0; it < 8; ++it){
            lA[it * 256 + t] = gA[it * 256 + t];
            lB[it * 256 + t] = gB[it * 256 + t];
        }
    }
    __syncthreads();

    int wid = t >> 6, lane = t & 63;
    int wr = (wid >> 1) * 64, wc = (wid & 1) * 64;
    int fr = lane & 15, fq = lane >> 4;

    f32x4 acc[4][4];
    #pragma unroll
    for (int m = 0; m < 4; ++m)
        #pragma unroll
        for (int n = 0; n < 4; ++n)
            acc[m][n] = (f32x4){0.f, 0.f, 0.f, 0.f};

    #pragma unroll
    for (int ks = 0; ks < 4; ++ks){
        int e0 = ks * 32 + fq * 8;
        bf16x8 a0 = frag_ld(As, wr + 0 * 16 + fr, e0);
        bf16x8 a1 = frag_ld(As, wr + 1 * 16 + fr, e0);
        bf16x8 a2 = frag_ld(As, wr + 2 * 16 + fr, e0);
        bf16x8 a3 = frag_ld(As, wr + 3 * 16 + fr, e0);
        bf16x8 b0 = frag_ld(Bs, wc + 0 * 16 + fr, e0);
        bf16x8 b1 = frag_ld(Bs, wc + 1 * 16 + fr, e0);
        bf16x8 b2 = frag_ld(Bs, wc + 2 * 16 + fr, e0);
        bf16x8 b3 = frag_ld(Bs, wc + 3 * 16 + fr, e0);
        acc[0][0] = __builtin_amdgcn_mfma_f32_16x16x32_bf16(a0, b0, acc[0][0], 0, 0, 0);
        acc[0][1] = __builtin_amdgcn_mfma_f32_16x16x32_bf16(a0, b1, acc[0][1], 0, 0, 0);
        acc[0][2] = __builtin_amdgcn_mfma_f32_16x16x32_bf16(a0, b2, acc[0][2], 0, 0, 0);
        acc[0][3] = __builtin_amdgcn_mfma_f32_16x16x32_bf16(a0, b3, acc[0][3], 0, 0, 0);
        acc[1][0] = __builtin_amdgcn_mfma_f32_16x16x32_bf16(a1, b0, acc[1][0], 0, 0, 0);
        acc[1][1] = __builtin_amdgcn_mfma_f32_16x16x32_bf16(a1, b1, acc[1][1], 0, 0, 0);
        acc[1][2] = __builtin_amdgcn_mfma_f32_16x16x32_bf16(a1, b2, acc[1][2], 0, 0, 0);
        acc[1][3] = __builtin_amdgcn_mfma_f32_16x16x32_bf16(a1, b3, acc[1][3], 0, 0, 0);
        acc[2][0] = __builtin_amdgcn_mfma_f32_16x16x32_bf16(a2, b0, acc[2][0], 0, 0, 0);
        acc[2][1] = __builtin_amdgcn_mfma_f32_16x16x32_bf16(a2, b1, acc[2][1], 0, 0, 0);
        acc[2][2] = __builtin_amdgcn_mfma_f32_16x16x32_bf16(a2, b2, acc[2][2], 0, 0, 0);
        acc[2][3] = __builtin_amdgcn_mfma_f32_16x16x32_bf16(a2, b3, acc[2][3], 0, 0, 0);
        acc[3][0] = __builtin_amdgcn_mfma_f32_16x16x32_bf16(a3, b0, acc[3][0], 0, 0, 0);
        acc[3][1] = __builtin_amdgcn_mfma_f32_16x16x32_bf16(a3, b1, acc[3][1], 0, 0, 0);
        acc[3][2] = __builtin_amdgcn_mfma_f32_16x16x32_bf16(a3, b2, acc[3][2], 0, 0, 0);
        acc[3][3] = __builtin_amdgcn_mfma_f32_16x16x32_bf16(a3, b3, acc[3][3], 0, 0, 0);
    }

    const float invT = 1.0f / 0.07f;
    int srow0 = blockIdx.y * 128 + wr + fq * 4;
    int scol0 = colbase + wc + fr;
    #pragma unroll
    for (int m = 0; m < 4; ++m){
        #pragma unroll
        for (int n = 0; n < 4; ++n){
            f32x4 c = acc[m][n];
            #pragma unroll
            for (int j = 0; j < 4; ++j)
                simz[(size_t)(srow0 + m * 16 + j) * BB + scol0 + n * 16] = c[j] * invT;
        }
    }
}

// ---------- slim stats: bitmasks + M=s_self + exact select + single LSE reduce ----------
__global__ __launch_bounds__(256) void krn_stats(const float* __restrict__ sim, size_t simStride,
                                                 const ushort* __restrict__ negmask,
                                                 const ushort* __restrict__ posmask,
                                                 const int* __restrict__ NCg,
                                                 const float* __restrict__ PWSg,
                                                 const float* __restrict__ PSIMg,
                                                 const int* __restrict__ kflags,
                                                 float* __restrict__ rowloss, int r0){
    __shared__ int hist[NBALLOC];
    __shared__ int wsum[4];
    __shared__ float redf[4];
    __shared__ unsigned selb[3];
    __shared__ unsigned sel2[2];
    __shared__ int cnt;
    __shared__ unsigned list[96];

    int t = threadIdx.x;
    int bi = blockIdx.y;
    int row = blockIdx.x;
    int i = r0 + row;

    #pragma unroll
    for (int e = 0; e < CHUNK; ++e) hist[t + e * 256] = 0;

    unsigned negU = negmask[i * 256 + t];
    unsigned posU = posmask[i * 256 + t];
    const float* srow = sim + (size_t)bi * simStride + (size_t)row * BB;
    const float4* sp = (const float4*)srow;
    float M = srow[i];              // s_self ~= row max (M cancels analytically)

    int kk = kflags[0], anyneg = kflags[1];
    int NCv = NCg[i];
    int mode = anyneg ? ((NCv <= kk) ? 1 : 0) : 2;   // 0: top-k, 1: all negs, 2: self_mask

    float s[16];
    __syncthreads();    // hist zero visible

    // pass A: loads + neg histogram + mode-base denominator
    #pragma unroll
    for (int e = 0; e < 4; ++e){
        float4 sv = sp[t + e * 256];
        s[e * 4 + 0] = sv.x; s[e * 4 + 1] = sv.y;
        s[e * 4 + 2] = sv.z; s[e * 4 + 3] = sv.w;
    }
    #pragma unroll
    for (int idx = 0; idx < 16; ++idx)
        if (negU & (1u << idx))
            atomicAdd(&hist[(fkey(s[idx]) - KLO) >> SH0], 1);

    unsigned em = (mode == 2) ? 0xFFFFu : ((mode == 1) ? (negU | posU) : posU);
    float El = 0.f;
    #pragma unroll
    for (int idx = 0; idx < 16; ++idx)
        if (em & (1u << idx)) El += __expf(s[idx] - M);
    __syncthreads();    // hist atomics done

    unsigned ukth = 0;
    int rfin = 0;
    if (mode == 0){
        unsigned klo = KLO, khi = KHI;
        int sh = SH0;
        int rp = kk;
        bool ready = true;
        while (true){
            if (klo == khi){ ukth = klo; rfin = rp; break; }
            if (!ready){
                #pragma unroll
                for (int e = 0; e < CHUNK; ++e) hist[t + e * 256] = 0;
                __syncthreads();
                #pragma unroll
                for (int idx = 0; idx < 16; ++idx){
                    if (negU & (1u << idx)){
                        unsigned u = fkey(s[idx]);
                        if (u >= klo && u <= khi)
                            atomicAdd(&hist[(u - klo) >> sh], 1);
                    }
                }
                __syncthreads();
            }
            ready = false;
            int g = 255 - t;
            int base = g * CHUNK;
            int ls = 0;
            #pragma unroll
            for (int e = 0; e < CHUNK; ++e) ls += hist[base + e];
            int v = ls;
            #pragma unroll
            for (int o = 1; o < 64; o <<= 1){
                int u2 = __shfl_up(v, o);
                if ((t & 63) >= o) v += u2;
            }
            if ((t & 63) == 63) wsum[t >> 6] = v;
            __syncthreads();
            int w = t >> 6;
            int pre = (w > 0 ? wsum[0] : 0) + (w > 1 ? wsum[1] : 0) + (w > 2 ? wsum[2] : 0);
            v += pre;
            int aec = v - ls;
            if (aec < rp && rp <= v){
                int cum = aec;
                #pragma unroll
                for (int e = CHUNK - 1; e >= 0; --e){
                    int c = hist[base + e];
                    if (cum < rp && rp <= cum + c){
                        selb[0] = (unsigned)(base + e);
                        selb[1] = (unsigned)cum;
                        selb[2] = (unsigned)c;
                        break;
                    }
                    cum += c;
                }
            }
            __syncthreads();
            unsigned B = selb[0];
            int ae = (int)selb[1];
            int c  = (int)selb[2];
            rp -= ae;
            klo += B << sh;
            unsigned nhi = klo + ((1u << sh) - 1u);
            if (nhi < khi) khi = nhi;
            if (c <= 96){
                if (t == 0) cnt = 0;
                __syncthreads();
                #pragma unroll
                for (int idx = 0; idx < 16; ++idx){
                    if (negU & (1u << idx)){
                        unsigned u = fkey(s[idx]);
                        if (u >= klo && u <= khi){
                            int p = atomicAdd(&cnt, 1);
                            list[p] = u;
                        }
                    }
                }
                __syncthreads();
                int cc = cnt;
                if (t < cc){
                    unsigned kj = list[t];
                    int g2 = 0, e2 = 0;
                    for (int mm = 0; mm < cc; ++mm){
                        unsigned km = list[mm];
                        g2 += (km > kj) ? 1 : 0;
                        e2 += (km == kj) ? 1 : 0;
                    }
                    if (g2 < rp && rp <= g2 + e2){ sel2[0] = kj; sel2[1] = (unsigned)g2; }
                }
                __syncthreads();
                ukth = sel2[0];
                rfin = rp - (int)sel2[1];
                break;
            }
            {
                unsigned range = khi - klo;
                int bits = 32 - __clz(range);
                sh = (bits > 12) ? (bits - 12) : 0;
            }
            __syncthreads();
        }
        // add hard negatives above threshold to the denominator
        float skth = funkey(ukth);
        #pragma unroll
        for (int idx = 0; idx < 16; ++idx)
            if ((negU & (1u << idx)) && s[idx] > skth)
                El += __expf(s[idx] - M);
    }

    float Etot = blkSumF(El, redf);

    if (t == 0){
        if (mode == 0) Etot += (float)rfin * __expf(funkey(ukth) - M);
        if (mode == 2) Etot -= 1.0f;        // remove self: exp(s_self - M) = exp(0) = 1
        float PWSc  = PWSg[i];
        float PSIMc = PSIMg[(size_t)bi * BB + i];
        float logE = __logf(Etot + 1e-8f);
        float wl = (PSIMc - M * PWSc) - PWSc * logE;
        rowloss[bi * BB + i] = wl / fmaxf(PWSc, 1e-8f);
    }
}

// ---------- final deterministic reduction ----------
__global__ void krn_final(const float* __restrict__ rowloss, float* __restrict__ out){
    __shared__ float redf[4];
    int t = threadIdx.x;  // 256
    float total = 0.f;
    for (int b = 0; b < 3; ++b){
        float ssum = 0.f;
        for (int e = 0; e < 16; ++e) ssum += rowloss[b * BB + t + e * 256];
        float S = blkSumF(ssum, redf);
        total += S * (1.0f / BB);
    }
    if (t == 0) out[0] = -total / 3.0f;
}

extern "C" void kernel_launch(void* const* d_in, const int* in_sizes, int n_in,
                              void* d_out, int out_size, void* d_ws, size_t ws_size,
                              hipStream_t stream){
    const float* drug   = (const float*)d_in[0];
    const float* se     = (const float*)d_in[1];
    const float* labels = (const float*)d_in[2];
    float* out = (float*)d_out;
    char* ws = (char*)d_ws;

    const size_t zbytes = (size_t)3 * BB * DD * sizeof(ushort);        // 3 MB
    const size_t ytbytes = (size_t)3 * DD * BB * sizeof(float);        // 6.3 MB
    const size_t maskbytes = (size_t)BB * 256 * sizeof(ushort);        // 2 MB each
    const size_t tail = (size_t)(3 + 3 + 1 + 1 + 1 + 1) * BB * sizeof(float)
                      + ytbytes + 2 * maskbytes + 256;

    int slab = BB;
    while (slab > 128 && zbytes + tail + (size_t)3 * slab * BB * sizeof(float) > ws_size)
        slab >>= 1;
    size_t simStride = (size_t)slab * BB;

    ushort* Z      = (ushort*)ws;
    float* simbuf  = (float*)(ws + zbytes);
    size_t off     = zbytes + (size_t)3 * simStride * sizeof(float);
    float* rowloss = (float*)(ws + off);  off += (size_t)3 * BB * sizeof(float);
    float* PSIMc   = (float*)(ws + off);  off += (size_t)3 * BB * sizeof(float);
    float* wp      = (float*)(ws + off);  off += (size_t)BB * sizeof(float);
    float* wm      = (float*)(ws + off);  off += (size_t)BB * sizeof(float);
    float* PWSb    = (float*)(ws + off);  off += (size_t)BB * sizeof(float);
    int*   NCb     = (int*)(ws + off);    off += (size_t)BB * sizeof(int);
    int*   perm    = (int*)(ws + off);    off += (size_t)BB * sizeof(int);
    float* Yt      = (float*)(ws + off);  off += ytbytes;
    ushort* negmask= (ushort*)(ws + off); off += maskbytes;
    ushort* posmask= (ushort*)(ws + off); off += maskbytes;
    int*   ntot    = (int*)(ws + off);
    int*   kflags  = ntot + 2;

    hipMemsetAsync(ntot, 0, 2 * sizeof(int), stream);
    krn_normalize<<<dim3(BB, 3), 128, 0, stream>>>(drug, se, labels, Z, wp, wm);
    krn_labelstats<<<256, 256, 0, stream>>>(labels, NCb, PWSb, perm, ntot);
    krn_masks<<<256, 256, 0, stream>>>(labels, negmask, posmask);
    krn_calck<<<1, 1, 0, stream>>>(ntot, kflags);
    krn_prefix<<<dim3(DD, 3), 256, 0, stream>>>(Z, perm, wp, wm, Yt);
    krn_psim<<<dim3(BB / 32, 3), 256, 0, stream>>>(Z, perm, wp, wm, Yt, PSIMc);

    int nslab = BB / slab;
    for (int s2 = 0; s2 < nslab; ++s2){
        krn_gemm<<<dim3(BB / 128, slab / 128, 3), 256, 0, stream>>>(Z, simbuf, simStride, s2 * slab);
        krn_stats<<<dim3(slab, 3), 256, 0, stream>>>(simbuf, simStride, negmask, posmask,
                                                     NCb, PWSb, PSIMc, kflags, rowloss, s2 * slab);
    }
    krn_final<<<1, 256, 0, stream>>>(rowloss, out);
}

// Round 11
// 181.480 us; speedup vs baseline: 1.3257x; 1.0434x over previous
//
#include <hip/hip_runtime.h>
#include <math.h>

#define BB 4096
#define DD 128
#define KLO 0x3E7FFFFFu     /* fkey(-16.0f) */
#define KHI 0xC1800000u     /* fkey(+16.0f) */
#define SH0 19              /* first-level bin shift: 4193 bins over [KLO,KHI] */
#define CHUNK 17
#define NBALLOC 4352        /* 17*256 zero-padded hist allocation */

typedef __attribute__((ext_vector_type(8))) short bf16x8;
typedef __attribute__((ext_vector_type(8))) unsigned short u16x8;
typedef __attribute__((ext_vector_type(4))) float f32x4;

__device__ __forceinline__ unsigned fkey(float x){
    int b = __float_as_int(x);
    return (unsigned)(b ^ ((b >> 31) | 0x80000000));
}
__device__ __forceinline__ float funkey(unsigned u){
    unsigned b = (u & 0x80000000u) ? (u & 0x7fffffffu) : ~u;
    return __uint_as_float(b);
}
__device__ __forceinline__ float bf16f(ushort u){
    return __uint_as_float(((unsigned)u) << 16);
}

__device__ __forceinline__ float blkSumF(float v, volatile float* sh){
    #pragma unroll
    for (int o = 32; o > 0; o >>= 1) v += __shfl_down(v, o);
    int t = threadIdx.x;
    __syncthreads();
    if ((t & 63) == 0) sh[t >> 6] = v;
    __syncthreads();
    return (sh[0] + sh[1]) + (sh[2] + sh[3]);
}

// ---------- normalize -> bf16 (XOR-swizzled col) + wp/wm + zz of quantized row ----------
__global__ void krn_normalize(const float* __restrict__ drug, const float* __restrict__ se,
                              const float* __restrict__ labels,
                              ushort* __restrict__ Z,
                              float* __restrict__ wp, float* __restrict__ wm,
                              float* __restrict__ zzb){
    int row = blockIdx.x, br = blockIdx.y, t = threadIdx.x;  // blockDim = 128
    float dv = drug[row * DD + t];
    float sv = se[row * DD + t];
    float v = (br == 0) ? dv : ((br == 1) ? sv : dv * sv);
    float sq = v * v;
    #pragma unroll
    for (int o = 32; o > 0; o >>= 1) sq += __shfl_down(sq, o);
    __shared__ float sh[2];
    __shared__ float sh2[2];
    if ((t & 63) == 0) sh[t >> 6] = sq;
    __syncthreads();
    float nrm = sqrtf(sh[0] + sh[1]);
    float outv = v / fmaxf(nrm, 1e-12f);
    unsigned u = __float_as_uint(outv);
    unsigned r = (u + 0x7FFFu + ((u >> 16) & 1u)) >> 16;   // RNE bf16
    int col = t ^ ((row & 7) << 3);
    Z[((size_t)br * BB + row) * DD + col] = (ushort)r;
    // ||bf16(z)||^2 for the self-term subtraction
    float bq = bf16f((ushort)r);
    float s2 = bq * bq;
    #pragma unroll
    for (int o = 32; o > 0; o >>= 1) s2 += __shfl_down(s2, o);
    if ((t & 63) == 0) sh2[t >> 6] = s2;
    __syncthreads();
    if (t == 0) zzb[(size_t)br * BB + row] = sh2[0] + sh2[1];
    if (br == 0 && t == 0){
        float l = labels[row];
        wp[row] = __expf(l * (1.0f / 0.15f));
        wm[row] = __expf(l * (-1.0f / 0.15f));
    }
}

// ---------- label stats: NC[i], PWS[i] (self-excl), ntot, label-sort perm ----------
__global__ __launch_bounds__(256) void krn_labelstats(const float* __restrict__ labels,
                                                      int* __restrict__ NC,
                                                      float* __restrict__ PWS,
                                                      int* __restrict__ perm,
                                                      int* __restrict__ ntot){
    __shared__ float lab[BB];
    __shared__ int shi[4], shr[4];
    __shared__ float shf[4];
    int t = threadIdx.x;
    #pragma unroll
    for (int e = 0; e < 4; ++e)
        ((float4*)lab)[t + e * 256] = ((const float4*)labels)[t + e * 256];
    __syncthreads();
    int i0 = blockIdx.x * 16;
    int ctot = 0;
    for (int ii = 0; ii < 16; ++ii){
        int i = i0 + ii;
        float li = lab[i];
        int c = 0, rk = 0;
        float pws = 0.f;
        #pragma unroll
        for (int e = 0; e < 16; ++e){
            int j = t + e * 256;
            float lj = lab[j];
            float d = fabsf(li - lj);
            c += (d > 1.0f) ? 1 : 0;
            pws += __expf(d * (-1.0f / 0.15f));
            rk += (lj < li || (lj == li && j < i)) ? 1 : 0;
        }
        #pragma unroll
        for (int o = 32; o > 0; o >>= 1){
            c += __shfl_down(c, o);
            rk += __shfl_down(rk, o);
            pws += __shfl_down(pws, o);
        }
        __syncthreads();
        if ((t & 63) == 0){ int w = t >> 6; shi[w] = c; shr[w] = rk; shf[w] = pws; }
        __syncthreads();
        if (t == 0){
            int C = (shi[0] + shi[1]) + (shi[2] + shi[3]);
            int R = (shr[0] + shr[1]) + (shr[2] + shr[3]);
            float P = (shf[0] + shf[1]) + (shf[2] + shf[3]);
            NC[i] = C;
            PWS[i] = P - 1.0f;   // exclude self (expf(-0)=1 exactly)
            perm[R] = i;
            ctot += C;
        }
    }
    if (t == 0) atomicAdd(ntot, ctot);
}

// ---------- bitmask tables: bit e*4+c covers j = 4t + 1024e + c ----------
__global__ __launch_bounds__(256) void krn_masks(const float* __restrict__ labels,
                                                 ushort* __restrict__ negmask,
                                                 ushort* __restrict__ posmask){
    __shared__ float lab[BB];
    int t = threadIdx.x;
    #pragma unroll
    for (int e = 0; e < 4; ++e)
        ((float4*)lab)[t + e * 256] = ((const float4*)labels)[t + e * 256];
    __syncthreads();
    float lj[16];
    #pragma unroll
    for (int e = 0; e < 4; ++e)
        #pragma unroll
        for (int c = 0; c < 4; ++c)
            lj[e * 4 + c] = lab[4 * t + 1024 * e + c];
    int i0 = blockIdx.x * 16;
    for (int ii = 0; ii < 16; ++ii){
        int i = i0 + ii;
        float li = lab[i];
        unsigned nb = 0, pb = 0;
        #pragma unroll
        for (int e = 0; e < 4; ++e){
            #pragma unroll
            for (int c = 0; c < 4; ++c){
                int idx = e * 4 + c;
                int j = 4 * t + 1024 * e + c;
                float d = fabsf(li - lj[idx]);
                if (d > 1.0f) nb |= 1u << idx;
                else if (d < 0.34538776f && j != i) pb |= 1u << idx;   // pw > 0.1
            }
        }
        negmask[i * 256 + t] = (ushort)nb;
        posmask[i * 256 + t] = (ushort)pb;
    }
}

__global__ void krn_calck(const int* __restrict__ ntot, int* __restrict__ kflags){
    int N = *ntot;
    int k = N >> 13;            // trunc((N/4096)*0.5), exact
    if (k < 1) k = 1;
    if (k > BB - 1) k = BB - 1;
    kflags[0] = k;
    kflags[1] = (N > 0) ? 1 : 0;
}

// ---------- sorted transpose: Zt[b][d][r] = z_{perm[r]}[d] (+ sorted wp/wm) ----------
__global__ __launch_bounds__(256) void krn_sortz(const ushort* __restrict__ Z,
                                                 const int* __restrict__ perm,
                                                 const float* __restrict__ wp,
                                                 const float* __restrict__ wm,
                                                 ushort* __restrict__ Zt,
                                                 float* __restrict__ wps,
                                                 float* __restrict__ wms){
    __shared__ ushort tile[64][130];
    __shared__ int pj[64];
    int b = blockIdx.y, t = threadIdx.x;
    int r0 = blockIdx.x * 64;
    if (t < 64) pj[t] = perm[r0 + t];
    __syncthreads();
    if (t < 64 && b == 0){
        int j = pj[t];
        wps[r0 + t] = wp[j];
        wms[r0 + t] = wm[j];
    }
    {
        int rr = t >> 2, q = t & 3;
        int j = pj[rr];
        int sw = j & 7;
        const u16x8* zr = (const u16x8*)(Z + ((size_t)b * BB + j) * DD);
        #pragma unroll
        for (int k = 0; k < 4; ++k){
            int c = q * 4 + k;              // d-chunk index (8 elems)
            u16x8 v8 = zr[c ^ sw];          // undo column swizzle at chunk granularity
            #pragma unroll
            for (int dl = 0; dl < 8; ++dl)
                tile[rr][c * 8 + dl] = v8[dl];
        }
    }
    __syncthreads();
    {
        int d = t >> 1, h = t & 1;
        ushort* ztp = Zt + ((size_t)b * DD + d) * BB + r0 + h * 32;
        #pragma unroll
        for (int g = 0; g < 8; ++g){
            ushort4 w4;
            w4.x = tile[h * 32 + g * 4 + 0][d];
            w4.y = tile[h * 32 + g * 4 + 1][d];
            w4.z = tile[h * 32 + g * 4 + 2][d];
            w4.w = tile[h * 32 + g * 4 + 3][d];
            *(ushort4*)(ztp + g * 4) = w4;
        }
    }
}

// ---------- coalesced prefix/suffix scans: Pt[b][d][r] = z*(wm_j*P<=r + wp_j*S>r) ----------
__global__ __launch_bounds__(256) void krn_prefix(const ushort* __restrict__ Zt,
                                                  const float* __restrict__ wps,
                                                  const float* __restrict__ wms,
                                                  float* __restrict__ Pt){
    int d = blockIdx.x, b = blockIdx.y, t = threadIdx.x;
    const ushort* zt = Zt + ((size_t)b * DD + d) * BB;
    u16x8 z0 = ((const u16x8*)zt)[t * 2];
    u16x8 z1 = ((const u16x8*)zt)[t * 2 + 1];
    float zv[16], wpj[16], wmj[16], uu[16], vv[16];
    #pragma unroll
    for (int k = 0; k < 4; ++k){
        float4 a = ((const float4*)wps)[t * 4 + k];
        float4 m4 = ((const float4*)wms)[t * 4 + k];
        wpj[k*4+0] = a.x; wpj[k*4+1] = a.y; wpj[k*4+2] = a.z; wpj[k*4+3] = a.w;
        wmj[k*4+0] = m4.x; wmj[k*4+1] = m4.y; wmj[k*4+2] = m4.z; wmj[k*4+3] = m4.w;
    }
    float tu = 0.f, tv = 0.f;
    #pragma unroll
    for (int q = 0; q < 16; ++q){
        zv[q] = bf16f(q < 8 ? z0[q] : z1[q - 8]);
        uu[q] = wpj[q] * zv[q];
        vv[q] = wmj[q] * zv[q];
        tu += uu[q];
        tv += vv[q];
    }
    int lane = t & 63, w = t >> 6;
    float xu = tu, xv = tv;
    #pragma unroll
    for (int o = 1; o < 64; o <<= 1){
        float y1 = __shfl_up(xu, o);   if (lane >= o)      xu += y1;
        float y2 = __shfl_down(xv, o); if (lane < 64 - o)  xv += y2;
    }
    __shared__ float wU[4], wV[4];
    if (lane == 63) wU[w] = xu;
    if (lane == 0)  wV[w] = xv;
    __syncthreads();
    float preU = 0.f, sufV = 0.f;
    #pragma unroll
    for (int ww = 0; ww < 4; ++ww){
        if (ww < w) preU += wU[ww];
        if (ww > w) sufV += wV[ww];
    }
    float offU   = preU + (xu - tu);   // exclusive prefix across threads
    float exSufV = sufV + (xv - tv);   // exclusive suffix across threads
    float acc = 0.f;
    #pragma unroll
    for (int q = 15; q >= 0; --q){     // element suffix (strictly greater)
        float S = exSufV + acc;
        acc += vv[q];
        vv[q] = S;
    }
    float* ptp = Pt + ((size_t)b * DD + d) * BB + t * 16;
    acc = 0.f;
    #pragma unroll
    for (int q = 0; q < 16; ++q){
        acc += uu[q];
        float P = offU + acc;          // inclusive prefix (contains self)
        ptp[q] = zv[q] * (wmj[q] * P + wpj[q] * vv[q]);
    }
}

// ---------- PSIMc[b][j]: streaming column sum of Pt minus self term ----------
__global__ __launch_bounds__(256) void krn_psim(const float* __restrict__ Pt,
                                                const int* __restrict__ perm,
                                                const float* __restrict__ wps,
                                                const float* __restrict__ wms,
                                                const float* __restrict__ zzb,
                                                float* __restrict__ PSIMc){
    int b = blockIdx.y;
    int r = blockIdx.x * 256 + threadIdx.x;
    const float* pt = Pt + (size_t)b * DD * BB + r;
    float acc = 0.f;
    #pragma unroll 8
    for (int d = 0; d < DD; ++d) acc += pt[(size_t)d * BB];
    int j = perm[r];
    float self = wps[r] * wms[r] * zzb[(size_t)b * BB + j];
    PSIMc[(size_t)b * BB + j] = (acc - self) * (1.0f / 0.07f);
}

// ---------- bf16 MFMA GEMM (proven): sim[z] = (Z_z Z_z^T)/T ----------
__device__ __forceinline__ bf16x8 frag_ld(const ushort* base, int row, int e0){
    int e = e0 ^ ((row & 7) << 3);
    return *(const bf16x8*)(base + row * DD + e);
}

__global__ __launch_bounds__(256) void krn_gemm(const ushort* __restrict__ Z,
                                                float* __restrict__ sim, size_t simStride,
                                                int r0){
    __shared__ ushort As[128 * DD];
    __shared__ ushort Bs[128 * DD];
    const ushort* Zb = Z + (size_t)blockIdx.z * (BB * DD);
    float* simz = sim + (size_t)blockIdx.z * simStride;
    int t = threadIdx.x;
    int rowbase = r0 + blockIdx.y * 128;
    int colbase = blockIdx.x * 128;

    {
        const float4* gA = (const float4*)(Zb + (size_t)rowbase * DD);
        const float4* gB = (const float4*)(Zb + (size_t)colbase * DD);
        float4* lA = (float4*)As;
        float4* lB = (float4*)Bs;
        #pragma unroll
        for (int it = 0; it < 8; ++it){
            lA[it * 256 + t] = gA[it * 256 + t];
            lB[it * 256 + t] = gB[it * 256 + t];
        }
    }
    __syncthreads();

    int wid = t >> 6, lane = t & 63;
    int wr = (wid >> 1) * 64, wc = (wid & 1) * 64;
    int fr = lane & 15, fq = lane >> 4;

    f32x4 acc[4][4];
    #pragma unroll
    for (int m = 0; m < 4; ++m)
        #pragma unroll
        for (int n = 0; n < 4; ++n)
            acc[m][n] = (f32x4){0.f, 0.f, 0.f, 0.f};

    #pragma unroll
    for (int ks = 0; ks < 4; ++ks){
        int e0 = ks * 32 + fq * 8;
        bf16x8 a0 = frag_ld(As, wr + 0 * 16 + fr, e0);
        bf16x8 a1 = frag_ld(As, wr + 1 * 16 + fr, e0);
        bf16x8 a2 = frag_ld(As, wr + 2 * 16 + fr, e0);
        bf16x8 a3 = frag_ld(As, wr + 3 * 16 + fr, e0);
        bf16x8 b0 = frag_ld(Bs, wc + 0 * 16 + fr, e0);
        bf16x8 b1 = frag_ld(Bs, wc + 1 * 16 + fr, e0);
        bf16x8 b2 = frag_ld(Bs, wc + 2 * 16 + fr, e0);
        bf16x8 b3 = frag_ld(Bs, wc + 3 * 16 + fr, e0);
        acc[0][0] = __builtin_amdgcn_mfma_f32_16x16x32_bf16(a0, b0, acc[0][0], 0, 0, 0);
        acc[0][1] = __builtin_amdgcn_mfma_f32_16x16x32_bf16(a0, b1, acc[0][1], 0, 0, 0);
        acc[0][2] = __builtin_amdgcn_mfma_f32_16x16x32_bf16(a0, b2, acc[0][2], 0, 0, 0);
        acc[0][3] = __builtin_amdgcn_mfma_f32_16x16x32_bf16(a0, b3, acc[0][3], 0, 0, 0);
        acc[1][0] = __builtin_amdgcn_mfma_f32_16x16x32_bf16(a1, b0, acc[1][0], 0, 0, 0);
        acc[1][1] = __builtin_amdgcn_mfma_f32_16x16x32_bf16(a1, b1, acc[1][1], 0, 0, 0);
        acc[1][2] = __builtin_amdgcn_mfma_f32_16x16x32_bf16(a1, b2, acc[1][2], 0, 0, 0);
        acc[1][3] = __builtin_amdgcn_mfma_f32_16x16x32_bf16(a1, b3, acc[1][3], 0, 0, 0);
        acc[2][0] = __builtin_amdgcn_mfma_f32_16x16x32_bf16(a2, b0, acc[2][0], 0, 0, 0);
        acc[2][1] = __builtin_amdgcn_mfma_f32_16x16x32_bf16(a2, b1, acc[2][1], 0, 0, 0);
        acc[2][2] = __builtin_amdgcn_mfma_f32_16x16x32_bf16(a2, b2, acc[2][2], 0, 0, 0);
        acc[2][3] = __builtin_amdgcn_mfma_f32_16x16x32_bf16(a2, b3, acc[2][3], 0, 0, 0);
        acc[3][0] = __builtin_amdgcn_mfma_f32_16x16x32_bf16(a3, b0, acc[3][0], 0, 0, 0);
        acc[3][1] = __builtin_amdgcn_mfma_f32_16x16x32_bf16(a3, b1, acc[3][1], 0, 0, 0);
        acc[3][2] = __builtin_amdgcn_mfma_f32_16x16x32_bf16(a3, b2, acc[3][2], 0, 0, 0);
        acc[3][3] = __builtin_amdgcn_mfma_f32_16x16x32_bf16(a3, b3, acc[3][3], 0, 0, 0);
    }

    const float invT = 1.0f / 0.07f;
    int srow0 = blockIdx.y * 128 + wr + fq * 4;
    int scol0 = colbase + wc + fr;
    #pragma unroll
    for (int m = 0; m < 4; ++m){
        #pragma unroll
        for (int n = 0; n < 4; ++n){
            f32x4 c = acc[m][n];
            #pragma unroll
            for (int j = 0; j < 4; ++j)
                simz[(size_t)(srow0 + m * 16 + j) * BB + scol0 + n * 16] = c[j] * invT;
        }
    }
}

// ---------- slim stats (R10-proven): bitmasks + M=s_self + exact select + LSE ----------
__global__ __launch_bounds__(256) void krn_stats(const float* __restrict__ sim, size_t simStride,
                                                 const ushort* __restrict__ negmask,
                                                 const ushort* __restrict__ posmask,
                                                 const int* __restrict__ NCg,
                                                 const float* __restrict__ PWSg,
                                                 const float* __restrict__ PSIMg,
                                                 const int* __restrict__ kflags,
                                                 float* __restrict__ rowloss, int r0){
    __shared__ int hist[NBALLOC];
    __shared__ int wsum[4];
    __shared__ float redf[4];
    __shared__ unsigned selb[3];
    __shared__ unsigned sel2[2];
    __shared__ int cnt;
    __shared__ unsigned list[96];

    int t = threadIdx.x;
    int bi = blockIdx.y;
    int row = blockIdx.x;
    int i = r0 + row;

    #pragma unroll
    for (int e = 0; e < CHUNK; ++e) hist[t + e * 256] = 0;

    unsigned negU = negmask[i * 256 + t];
    unsigned posU = posmask[i * 256 + t];
    const float* srow = sim + (size_t)bi * simStride + (size_t)row * BB;
    const float4* sp = (const float4*)srow;
    float M = srow[i];              // s_self ~= row max (M cancels analytically)

    int kk = kflags[0], anyneg = kflags[1];
    int NCv = NCg[i];
    int mode = anyneg ? ((NCv <= kk) ? 1 : 0) : 2;   // 0: top-k, 1: all negs, 2: self_mask

    float s[16];
    __syncthreads();    // hist zero visible

    #pragma unroll
    for (int e = 0; e < 4; ++e){
        float4 sv = sp[t + e * 256];
        s[e * 4 + 0] = sv.x; s[e * 4 + 1] = sv.y;
        s[e * 4 + 2] = sv.z; s[e * 4 + 3] = sv.w;
    }
    #pragma unroll
    for (int idx = 0; idx < 16; ++idx)
        if (negU & (1u << idx))
            atomicAdd(&hist[(fkey(s[idx]) - KLO) >> SH0], 1);

    unsigned em = (mode == 2) ? 0xFFFFu : ((mode == 1) ? (negU | posU) : posU);
    float El = 0.f;
    #pragma unroll
    for (int idx = 0; idx < 16; ++idx)
        if (em & (1u << idx)) El += __expf(s[idx] - M);
    __syncthreads();    // hist atomics done

    unsigned ukth = 0;
    int rfin = 0;
    if (mode == 0){
        unsigned klo = KLO, khi = KHI;
        int sh = SH0;
        int rp = kk;
        bool ready = true;
        while (true){
            if (klo == khi){ ukth = klo; rfin = rp; break; }
            if (!ready){
                #pragma unroll
                for (int e = 0; e < CHUNK; ++e) hist[t + e * 256] = 0;
                __syncthreads();
                #pragma unroll
                for (int idx = 0; idx < 16; ++idx){
                    if (negU & (1u << idx)){
                        unsigned u = fkey(s[idx]);
                        if (u >= klo && u <= khi)
                            atomicAdd(&hist[(u - klo) >> sh], 1);
                    }
                }
                __syncthreads();
            }
            ready = false;
            int g = 255 - t;
            int base = g * CHUNK;
            int ls = 0;
            #pragma unroll
            for (int e = 0; e < CHUNK; ++e) ls += hist[base + e];
            int v = ls;
            #pragma unroll
            for (int o = 1; o < 64; o <<= 1){
                int u2 = __shfl_up(v, o);
                if ((t & 63) >= o) v += u2;
            }
            if ((t & 63) == 63) wsum[t >> 6] = v;
            __syncthreads();
            int w = t >> 6;
            int pre = (w > 0 ? wsum[0] : 0) + (w > 1 ? wsum[1] : 0) + (w > 2 ? wsum[2] : 0);
            v += pre;
            int aec = v - ls;
            if (aec < rp && rp <= v){
                int cum = aec;
                #pragma unroll
                for (int e = CHUNK - 1; e >= 0; --e){
                    int c = hist[base + e];
                    if (cum < rp && rp <= cum + c){
                        selb[0] = (unsigned)(base + e);
                        selb[1] = (unsigned)cum;
                        selb[2] = (unsigned)c;
                        break;
                    }
                    cum += c;
                }
            }
            __syncthreads();
            unsigned B = selb[0];
            int ae = (int)selb[1];
            int c  = (int)selb[2];
            rp -= ae;
            klo += B << sh;
            unsigned nhi = klo + ((1u << sh) - 1u);
            if (nhi < khi) khi = nhi;
            if (c <= 96){
                if (t == 0) cnt = 0;
                __syncthreads();
                #pragma unroll
                for (int idx = 0; idx < 16; ++idx){
                    if (negU & (1u << idx)){
                        unsigned u = fkey(s[idx]);
                        if (u >= klo && u <= khi){
                            int p = atomicAdd(&cnt, 1);
                            list[p] = u;
                        }
                    }
                }
                __syncthreads();
                int cc = cnt;
                if (t < cc){
                    unsigned kj = list[t];
                    int g2 = 0, e2 = 0;
                    for (int mm = 0; mm < cc; ++mm){
                        unsigned km = list[mm];
                        g2 += (km > kj) ? 1 : 0;
                        e2 += (km == kj) ? 1 : 0;
                    }
                    if (g2 < rp && rp <= g2 + e2){ sel2[0] = kj; sel2[1] = (unsigned)g2; }
                }
                __syncthreads();
                ukth = sel2[0];
                rfin = rp - (int)sel2[1];
                break;
            }
            {
                unsigned range = khi - klo;
                int bits = 32 - __clz(range);
                sh = (bits > 12) ? (bits - 12) : 0;
            }
            __syncthreads();
        }
        float skth = funkey(ukth);
        #pragma unroll
        for (int idx = 0; idx < 16; ++idx)
            if ((negU & (1u << idx)) && s[idx] > skth)
                El += __expf(s[idx] - M);
    }

    float Etot = blkSumF(El, redf);

    if (t == 0){
        if (mode == 0) Etot += (float)rfin * __expf(funkey(ukth) - M);
        if (mode == 2) Etot -= 1.0f;        // remove self: exp(s_self - M) = 1
        float PWSc  = PWSg[i];
        float PSIMc = PSIMg[(size_t)bi * BB + i];
        float logE = __logf(Etot + 1e-8f);
        float wl = (PSIMc - M * PWSc) - PWSc * logE;
        rowloss[bi * BB + i] = wl / fmaxf(PWSc, 1e-8f);
    }
}

// ---------- final deterministic reduction ----------
__global__ void krn_final(const float* __restrict__ rowloss, float* __restrict__ out){
    __shared__ float redf[4];
    int t = threadIdx.x;  // 256
    float total = 0.f;
    for (int b = 0; b < 3; ++b){
        float ssum = 0.f;
        for (int e = 0; e < 16; ++e) ssum += rowloss[b * BB + t + e * 256];
        float S = blkSumF(ssum, redf);
        total += S * (1.0f / BB);
    }
    if (t == 0) out[0] = -total / 3.0f;
}

extern "C" void kernel_launch(void* const* d_in, const int* in_sizes, int n_in,
                              void* d_out, int out_size, void* d_ws, size_t ws_size,
                              hipStream_t stream){
    const float* drug   = (const float*)d_in[0];
    const float* se     = (const float*)d_in[1];
    const float* labels = (const float*)d_in[2];
    float* out = (float*)d_out;
    char* ws = (char*)d_ws;

    const size_t zbytes   = (size_t)3 * BB * DD * sizeof(ushort);   // 3 MB
    const size_t ztbytes  = (size_t)3 * BB * DD * sizeof(ushort);   // 3 MB
    const size_t ptbytes  = (size_t)3 * DD * BB * sizeof(float);    // 6.3 MB
    const size_t maskbytes= (size_t)BB * 256 * sizeof(ushort);      // 2 MB each
    const size_t tail = (size_t)(3 + 3 + 3 + 1 + 1 + 1 + 1 + 1 + 1 + 1) * BB * sizeof(float)
                      + ztbytes + ptbytes + 2 * maskbytes + 256;

    int slab = BB;
    while (slab > 128 && zbytes + tail + (size_t)3 * slab * BB * sizeof(float) > ws_size)
        slab >>= 1;
    size_t simStride = (size_t)slab * BB;

    ushort* Z      = (ushort*)ws;
    float* simbuf  = (float*)(ws + zbytes);
    size_t off     = zbytes + (size_t)3 * simStride * sizeof(float);
    float* rowloss = (float*)(ws + off);  off += (size_t)3 * BB * sizeof(float);
    float* PSIMc   = (float*)(ws + off);  off += (size_t)3 * BB * sizeof(float);
    float* zzb     = (float*)(ws + off);  off += (size_t)3 * BB * sizeof(float);
    float* wp      = (float*)(ws + off);  off += (size_t)BB * sizeof(float);
    float* wm      = (float*)(ws + off);  off += (size_t)BB * sizeof(float);
    float* wps     = (float*)(ws + off);  off += (size_t)BB * sizeof(float);
    float* wms     = (float*)(ws + off);  off += (size_t)BB * sizeof(float);
    float* PWSb    = (float*)(ws + off);  off += (size_t)BB * sizeof(float);
    int*   NCb     = (int*)(ws + off);    off += (size_t)BB * sizeof(int);
    int*   perm    = (int*)(ws + off);    off += (size_t)BB * sizeof(int);
    ushort* Zt     = (ushort*)(ws + off); off += ztbytes;
    float* Pt      = (float*)(ws + off);  off += ptbytes;
    ushort* negmask= (ushort*)(ws + off); off += maskbytes;
    ushort* posmask= (ushort*)(ws + off); off += maskbytes;
    int*   ntot    = (int*)(ws + off);
    int*   kflags  = ntot + 2;

    hipMemsetAsync(ntot, 0, 2 * sizeof(int), stream);
    krn_normalize<<<dim3(BB, 3), 128, 0, stream>>>(drug, se, labels, Z, wp, wm, zzb);
    krn_labelstats<<<256, 256, 0, stream>>>(labels, NCb, PWSb, perm, ntot);
    krn_masks<<<256, 256, 0, stream>>>(labels, negmask, posmask);
    krn_calck<<<1, 1, 0, stream>>>(ntot, kflags);
    krn_sortz<<<dim3(BB / 64, 3), 256, 0, stream>>>(Z, perm, wp, wm, Zt, wps, wms);
    krn_prefix<<<dim3(DD, 3), 256, 0, stream>>>(Zt, wps, wms, Pt);
    krn_psim<<<dim3(BB / 256, 3), 256, 0, stream>>>(Pt, perm, wps, wms, zzb, PSIMc);

    int nslab = BB / slab;
    for (int s2 = 0; s2 < nslab; ++s2){
        krn_gemm<<<dim3(BB / 128, slab / 128, 3), 256, 0, stream>>>(Z, simbuf, simStride, s2 * slab);
        krn_stats<<<dim3(slab, 3), 256, 0, stream>>>(simbuf, simStride, negmask, posmask,
                                                     NCb, PWSb, PSIMc, kflags, rowloss, s2 * slab);
    }
    krn_final<<<1, 256, 0, stream>>>(rowloss, out);
}